// Round 11
// baseline (322.809 us; speedup 1.0000x reference)
//
#include <hip/hip_runtime.h>
#include <hip/hip_fp16.h>

// GCNConv (PyG semantics) + eval-dropout(identity) + ReLU, fp32 in/out.
// N=100000 nodes, E=1600000 edges, D=64.
//
// 4-dispatch pipeline, zero global atomics:
//  K1 k_gemm_hist: blocks [0,NB1) = per-block LDS histogram of col buckets
//     (128 dest nodes each) -> hist[bk*NBUCK+bu] (pure stores);
//     blocks [NB1,..) = xw_h = fp16(x@W) via mfma_f32_16x16x32_bf16.
//  K2 k_scatter: self-scanning -- each block recomputes bucket totals + its
//     own prefix from hist (coalesced, L2-resident), LDS-scans totals ->
//     exact cursors; scatters packed=(row<<7)|(col&127) densely. bk==0
//     persists bstart[]. LDS atomics only.
//  K3 k_dis: per-bucket per-node hist -> disg = rsqrt(deg+1).
//  K4 k_gather: per bucket (512 thr): LDS hist+scan+sort, register gather
//     with per-edge disg[r], fused self-loop + bias + ReLU.

#define D 64
#define BW 128             // dest nodes per bucket
#define CAP 3072           // LDS sort capacity (bucket mean 2048, +22 sigma)
#define EPB 8192           // edges per hist/scatter block
#define MAXBUCK 800        // >= NBUCK (782)

typedef __attribute__((ext_vector_type(8))) short bf16x8;
typedef __attribute__((ext_vector_type(4))) float f32x4;

__device__ __forceinline__ unsigned short f2bf(float f) {   // RNE fp32->bf16
    unsigned u = __float_as_uint(f);
    u += 0x7FFFu + ((u >> 16) & 1u);
    return (unsigned short)(u >> 16);
}

// ---- K1: hist (blocks < NB1) || MFMA GEMM (blocks >= NB1) ------------------
// GEMM: A: m=lane&15, k=quad*8+j. C/D: col=lane&15, row=quad*4+reg (m89/m91).
__global__ __launch_bounds__(256, 4)
void k_gemm_hist(const float* __restrict__ x, const float* __restrict__ W,
                 unsigned short* __restrict__ xw_h, const int* __restrict__ col,
                 int* __restrict__ hist, int E, int N, int NB1, int NBUCK) {
    __shared__ float sh[4096];    // 16 KB: Ws for gemm, lh for hist
    int tid = threadIdx.x;
    if ((int)blockIdx.x < NB1) {
        // ---- histogram part ----
        int* lh = (int*)sh;
        int bk = blockIdx.x;
        for (int bu = tid; bu < NBUCK; bu += 256) lh[bu] = 0;
        __syncthreads();
        int base = bk * EPB;
#pragma unroll 4
        for (int i = tid; i < EPB; i += 256) {
            int e = base + i;
            if (e < E) atomicAdd(&lh[col[e] >> 7], 1);   // LDS only
        }
        __syncthreads();
        for (int bu = tid; bu < NBUCK; bu += 256)
            hist[bk * NBUCK + bu] = lh[bu];              // contiguous stores
        return;
    }
    // ---- GEMM part ----
    float* Ws = sh;
    for (int i = tid; i < 4096; i += 256) Ws[i] = W[i];
    __syncthreads();
    int lane = tid & 63, wv = tid >> 6;
    int m = lane & 15, quad = lane >> 4;
    bf16x8 Bf[4][2];
#pragma unroll
    for (int t = 0; t < 4; ++t)
#pragma unroll
        for (int s = 0; s < 2; ++s) {
            bf16x8 f;
#pragma unroll
            for (int j = 0; j < 8; ++j)
                f[j] = (short)f2bf(Ws[(s * 32 + quad * 8 + j) * 64 + t * 16 + m]);
            Bf[t][s] = f;
        }
    int row0 = ((blockIdx.x - NB1) * 4 + wv) * 16;
    if (row0 >= N) return;
    const float* xr = x + (size_t)(row0 + m) * 64 + quad * 8;
    float4 a0 = *(const float4*)(xr);
    float4 a1 = *(const float4*)(xr + 4);
    float4 a2 = *(const float4*)(xr + 32);
    float4 a3 = *(const float4*)(xr + 36);
    bf16x8 A0, A1;
    A0[0] = (short)f2bf(a0.x); A0[1] = (short)f2bf(a0.y);
    A0[2] = (short)f2bf(a0.z); A0[3] = (short)f2bf(a0.w);
    A0[4] = (short)f2bf(a1.x); A0[5] = (short)f2bf(a1.y);
    A0[6] = (short)f2bf(a1.z); A0[7] = (short)f2bf(a1.w);
    A1[0] = (short)f2bf(a2.x); A1[1] = (short)f2bf(a2.y);
    A1[2] = (short)f2bf(a2.z); A1[3] = (short)f2bf(a2.w);
    A1[4] = (short)f2bf(a3.x); A1[5] = (short)f2bf(a3.y);
    A1[6] = (short)f2bf(a3.z); A1[7] = (short)f2bf(a3.w);
    f32x4 acc[4];
#pragma unroll
    for (int t = 0; t < 4; ++t) {
        acc[t] = (f32x4){0.f, 0.f, 0.f, 0.f};
        acc[t] = __builtin_amdgcn_mfma_f32_16x16x32_bf16(A0, Bf[t][0], acc[t], 0, 0, 0);
        acc[t] = __builtin_amdgcn_mfma_f32_16x16x32_bf16(A1, Bf[t][1], acc[t], 0, 0, 0);
    }
#pragma unroll
    for (int t = 0; t < 4; ++t)
#pragma unroll
        for (int r = 0; r < 4; ++r)
            xw_h[(size_t)(row0 + quad * 4 + r) * 64 + t * 16 + m] =
                __half_as_ushort(__float2half(acc[t][r]));
}

// ---- K2: self-scanning scatter (no global scan, no global atomics) ---------
__global__ __launch_bounds__(256, 4)
void k_scatter(const int* __restrict__ row, const int* __restrict__ col,
               const int* __restrict__ hist, int* __restrict__ packed,
               int* __restrict__ bstart, int E, int NB1, int NBUCK) {
    __shared__ int pref[MAXBUCK];
    __shared__ int cur[MAXBUCK];
    __shared__ int wsum[4];
    int bk = blockIdx.x, tid = threadIdx.x;
    // per-bucket total + this block's prefix (coalesced across tid at fixed k)
    for (int bu = tid; bu < NBUCK; bu += 256) {
        int tot = 0, pf = 0;
        for (int k = 0; k < NB1; ++k) {
            int h = hist[k * NBUCK + bu];
            tot += h;
            pf += (k < bk) ? h : 0;
        }
        pref[bu] = pf;
        cur[bu] = tot;   // totals, temporarily
    }
    __syncthreads();
    // exclusive scan of totals -> base; cur = base + pref
    int i0 = tid * 4;
    int v0 = (i0 + 0 < NBUCK) ? cur[i0 + 0] : 0;
    int v1 = (i0 + 1 < NBUCK) ? cur[i0 + 1] : 0;
    int v2 = (i0 + 2 < NBUCK) ? cur[i0 + 2] : 0;
    int v3 = (i0 + 3 < NBUCK) ? cur[i0 + 3] : 0;
    int t4 = v0 + v1 + v2 + v3;
    int lane = tid & 63, wv = tid >> 6;
    int s = t4;
#pragma unroll
    for (int off = 1; off < 64; off <<= 1) {
        int u = __shfl_up(s, off);
        if (lane >= off) s += u;
    }
    if (lane == 63) wsum[wv] = s;
    __syncthreads();
    int woff = 0;
    for (int w = 0; w < 4; ++w) woff += (w < wv) ? wsum[w] : 0;
    int excl = woff + s - t4;
    __syncthreads();   // all totals consumed before cur is overwritten
    if (i0 + 0 < NBUCK) cur[i0 + 0] = excl + pref[i0 + 0];
    if (i0 + 1 < NBUCK) cur[i0 + 1] = excl + v0 + pref[i0 + 1];
    if (i0 + 2 < NBUCK) cur[i0 + 2] = excl + v0 + v1 + pref[i0 + 2];
    if (i0 + 3 < NBUCK) cur[i0 + 3] = excl + v0 + v1 + v2 + pref[i0 + 3];
    if (bk == 0) {     // persist bucket bases (pref==0 here)
        if (i0 + 0 < NBUCK) bstart[i0 + 0] = excl;
        if (i0 + 1 < NBUCK) bstart[i0 + 1] = excl + v0;
        if (i0 + 2 < NBUCK) bstart[i0 + 2] = excl + v0 + v1;
        if (i0 + 3 < NBUCK) bstart[i0 + 3] = excl + v0 + v1 + v2;
        if (tid == 0) bstart[NBUCK] = E;
    }
    __syncthreads();
    int base = bk * EPB;
#pragma unroll 4
    for (int i = tid; i < EPB; i += 256) {
        int e = base + i;
        if (e < E) {
            int c = col[e], r = row[e];
            int pos = atomicAdd(&cur[c >> 7], 1);   // LDS only
            packed[pos] = (r << 7) | (c & 127);
        }
    }
}

// ---- K3: per-node degree -> dis --------------------------------------------
__global__ void k_dis(const int* __restrict__ bstart, const int* __restrict__ packed,
                      float* __restrict__ disg, int N) {
    __shared__ int lh[BW];
    int b = blockIdx.x, tid = threadIdx.x;
    if (tid < BW) lh[tid] = 0;
    __syncthreads();
    int lo = bstart[b], hi = bstart[b + 1];
    for (int i = lo + tid; i < hi; i += 256)
        atomicAdd(&lh[packed[i] & 127], 1);
    __syncthreads();
    if (tid < BW) {
        int n = b * BW + tid;
        if (n < N) disg[n] = rsqrtf((float)(lh[tid] + 1));
    }
}

// ---- K4: fused sort + gather: one 512-thr block per bucket -----------------
__global__ __launch_bounds__(512, 4)
void k_gather(const int* __restrict__ bstart, const int* __restrict__ packed,
              const float* __restrict__ disg, const uint2* __restrict__ xwh,
              const float* __restrict__ bias, float4* __restrict__ out4, int N) {
    __shared__ int lh[BW], stt[BW], cur[BW];
    __shared__ int srtL[CAP];
    __shared__ int wsum[2];
    int b = blockIdx.x, tid = threadIdx.x;
    if (tid < BW) lh[tid] = 0;
    __syncthreads();
    int lo = bstart[b], hi = bstart[b + 1];
    int sz = min(hi - lo, CAP);
    const int* pk = packed + lo;
    for (int i = tid; i < sz; i += 512)
        atomicAdd(&lh[pk[i] & 127], 1);
    __syncthreads();
    int lane = tid & 63, wv = tid >> 6;
    int v = (tid < BW) ? lh[tid] : 0;
    int s = v;
#pragma unroll
    for (int off = 1; off < 64; off <<= 1) {
        int u = __shfl_up(s, off);
        if (lane >= off) s += u;
    }
    if (tid < BW && lane == 63) wsum[wv] = s;
    __syncthreads();
    if (tid < BW) {
        int st = ((wv == 1) ? wsum[0] : 0) + s - v;
        stt[tid] = st;
        cur[tid] = st;
    }
    __syncthreads();
    for (int i = tid; i < sz; i += 512) {
        int p = pk[i];
        int pos = atomicAdd(&cur[p & 127], 1);   // LDS only
        srtL[pos] = p >> 7;
    }
    __syncthreads();
    int q = lane >> 4;       // edge subset 0..3
    int l = lane & 15;       // 8-byte chunk: dims 4l..4l+3
    const float4 bb = ((const float4*)bias)[l];
#define ADDS(h, ww)                                                         \
    {                                                                       \
        __half2 h0 = *(__half2*)&(h).x, h1 = *(__half2*)&(h).y;             \
        float2 f0 = __half22float2(h0), f1 = __half22float2(h1);            \
        acc.x = fmaf((ww), f0.x, acc.x); acc.y = fmaf((ww), f0.y, acc.y);   \
        acc.z = fmaf((ww), f1.x, acc.z); acc.w = fmaf((ww), f1.y, acc.w);   \
    }
    for (int nn = wv * 16; nn < wv * 16 + 16; ++nn) {      // 8 waves x 16 nodes
        int node = b * BW + nn;
        if (node >= N) break;
        int k = lh[nn], s0 = stt[nn];
        float dn = rsqrtf((float)(k + 1));
        float4 acc = make_float4(0.f, 0.f, 0.f, 0.f);
        if (q == 0) {   // self-loop
            uint2 hs = xwh[(size_t)node * 16 + l];
            ADDS(hs, dn);
        }
        int j = q;
        for (; j + 12 < k; j += 16) {
            int r0 = srtL[s0 + j];
            int r1 = srtL[s0 + j + 4];
            int r2 = srtL[s0 + j + 8];
            int r3 = srtL[s0 + j + 12];
            float w0 = disg[r0], w1 = disg[r1], w2 = disg[r2], w3 = disg[r3];
            uint2 va = xwh[(size_t)r0 * 16 + l];
            uint2 vb = xwh[(size_t)r1 * 16 + l];
            uint2 vc = xwh[(size_t)r2 * 16 + l];
            uint2 vd = xwh[(size_t)r3 * 16 + l];
            ADDS(va, w0); ADDS(vb, w1); ADDS(vc, w2); ADDS(vd, w3);
        }
        for (; j < k; j += 4) {
            int r = srtL[s0 + j];
            float wr = disg[r];
            uint2 ve = xwh[(size_t)r * 16 + l];
            ADDS(ve, wr);
        }
#pragma unroll
        for (int mm = 16; mm < 64; mm <<= 1) {
            acc.x += __shfl_xor(acc.x, mm);
            acc.y += __shfl_xor(acc.y, mm);
            acc.z += __shfl_xor(acc.z, mm);
            acc.w += __shfl_xor(acc.w, mm);
        }
        if (q == 0) {
            float4 o;
            o.x = fmaxf(fmaf(dn, acc.x, bb.x), 0.f);
            o.y = fmaxf(fmaf(dn, acc.y, bb.y), 0.f);
            o.z = fmaxf(fmaf(dn, acc.z, bb.z), 0.f);
            o.w = fmaxf(fmaf(dn, acc.w, bb.w), 0.f);
            out4[(size_t)node * 16 + l] = o;
        }
    }
#undef ADDS
}

extern "C" void kernel_launch(void* const* d_in, const int* in_sizes, int n_in,
                              void* d_out, int out_size, void* d_ws, size_t ws_size,
                              hipStream_t stream) {
    const float* x    = (const float*)d_in[0];
    const int*   ei   = (const int*)d_in[1];   // int32 (JAX demotes int64)
    const float* W    = (const float*)d_in[2];
    const float* bias = (const float*)d_in[3];
    float* out = (float*)d_out;

    const int N = in_sizes[0] / D;
    const int E = in_sizes[1] / 2;
    const int* row = ei;       // edge_index[0] = sources
    const int* col = ei + E;   // edge_index[1] = destinations

    const int NBUCK = (N + BW - 1) / BW;        // 782
    const int NB1   = (E + EPB - 1) / EPB;      // 196
    const int NT    = (N + 15) / 16;            // 6250 M-tiles
    const int GB    = (NT + 3) / 4;             // 1563 gemm blocks

    char* ws = (char*)d_ws;
    size_t off = 0;
    unsigned short* xw_h = (unsigned short*)(ws + off);
    off += (size_t)N * D * sizeof(unsigned short);                        // 12.8 MB
    int*   packed = (int*)(ws + off);   off += (size_t)E * sizeof(int);   // 6.4 MB
    int*   hist   = (int*)(ws + off);   off += (size_t)NB1 * NBUCK * sizeof(int);
    int*   bstart = (int*)(ws + off);   off += (size_t)(NBUCK + 1) * sizeof(int);
    float* disg   = (float*)(ws + off); off += (size_t)N * sizeof(float);

    k_gemm_hist<<<NB1 + GB, 256, 0, stream>>>(x, W, xw_h, col, hist, E, N, NB1, NBUCK);
    k_scatter<<<NB1, 256, 0, stream>>>(row, col, hist, packed, bstart, E, NB1, NBUCK);
    k_dis<<<NBUCK, 256, 0, stream>>>(bstart, packed, disg, N);
    k_gather<<<NBUCK, 512, 0, stream>>>(bstart, packed, disg, (const uint2*)xw_h,
                                        bias, (float4*)out, N);
}